// Round 5
// baseline (32.898 us; speedup 1.0000x reference)
//
#include <hip/hip_runtime.h>
#include <math.h>

#define IN_CH   2048
#define OUT_CH  1000
#define NROWS   8192
#define GRID1   2048
#define RPB     4      // rows per block; 2048 x 4 = 8192 rows

#define BFLY(A, i, j) { float u_ = A[i], v_ = A[j]; A[i] = u_ + v_; A[j] = u_ - v_; }
#define RADIX8(A) \
    BFLY(A,0,1) BFLY(A,2,3) BFLY(A,4,5) BFLY(A,6,7) \
    BFLY(A,0,2) BFLY(A,1,3) BFLY(A,4,6) BFLY(A,5,7) \
    BFLY(A,0,4) BFLY(A,1,5) BFLY(A,2,6) BFLY(A,3,7)

// ---------------------------------------------------------------------------
// Kernel 1: streams 4 rows of x once per block. Accumulates sum(x^2) partial
// and computes FWHT(2048) per row, writing UNSCALED y[0..999] to out.
// Dead-subtree: outputs >=1024 are discarded and bit 10 is butterflied first,
// so only the (u0+u1) half survives round 0; rounds 1-2 run on waves 0-1.
// Bit-permuted LDS layouts (validated in rounds 2-3):
//   pi1: s0=e2 s1=e3 s2=e5 s3=e6 s4=e7 s5=e4 s6=e0 s7=e1 s8=e8 s9=e9 (e10=0)
//   pi2: s0=e5 s1=e6 s2=e0 s3=e1 s4=e8 s5=e7 s6=e2 s7=e3 s8=e4 s9=e9 (e10=0)
//   pi3: s0=e8 s1=e9 s2=e0 s3=e1 s4=e2 s5=0   s6=e5 s7=e6 s8=e7 s9=e3 s10=e4
// All reads are 2x (or 1x) ds_read_b128 with full 32-bank coverage; all
// writes are 2-way-aliased b32 (free on CDNA4).
// ---------------------------------------------------------------------------
__global__ __launch_bounds__(256) void fwht_sumsq_kernel(const float* __restrict__ x,
                                                         float* __restrict__ out,
                                                         float* __restrict__ partials) {
    const int t = threadIdx.x;
    const int bid = blockIdx.x;

    __shared__ __align__(16) float bufA[2048];
    __shared__ __align__(16) float bufB[1024];
    __shared__ float wsf[4];

    const int t0 = t & 1, t1 = (t >> 1) & 1, t2 = (t >> 2) & 1, t3 = (t >> 3) & 1;
    const int t4 = (t >> 4) & 1, t5 = (t >> 5) & 1, t6 = (t >> 6) & 1, t7 = (t >> 7) & 1;

    // addresses (constant per thread across rows)
    const int bW1 = t0 + 2 * t1 + 4 * t3 + 8 * t4 + 16 * t5 + 32 * t2 + 256 * t6 + 512 * t7;
    const int bR1 = 4 * (t & 7) + 64 * (t >> 3);                                    // t<128
    const int bW2 = t0 + 2 * t1 + 4 * t3 + 8 * t4 + 16 * t5 + 32 * t2 + 512 * t6;   // t7=0
    const int bR2 = 4 * (t & 7) + 512 * t3 + 64 * t4 + 128 * t5 + 256 * t6;         // t7=0
    const int bW3 = t2 + 2 * t3 + 4 * t0 + 8 * t1 + 16 * t4 + 512 * t5 + 1024 * t6; // t7=0
    const int bR3 = 4 * (t & 7) + 512 * t3 + 1024 * t4 + 64 * t5 + 128 * t6 + 256 * t7;

    const float4* xr = (const float4*)(x + (size_t)bid * RPB * IN_CH);

    float ss = 0.f;
    float4 cu0 = xr[t], cu1 = xr[t + 256];

#pragma unroll
    for (int r = 0; r < RPB; ++r) {
        float4 nu0, nu1;
        if (r + 1 < RPB) {              // prefetch next row
            nu0 = xr[(r + 1) * 512 + t];
            nu1 = xr[(r + 1) * 512 + t + 256];
        }

        ss += cu0.x * cu0.x + cu0.y * cu0.y + cu0.z * cu0.z + cu0.w * cu0.w
            + cu1.x * cu1.x + cu1.y * cu1.y + cu1.z * cu1.z + cu1.w * cu1.w;

        // round 0: bit-10 butterfly (keep e10=0 half) + radix-4 on bits {0,1}
        float a[4] = {cu0.x + cu1.x, cu0.y + cu1.y, cu0.z + cu1.z, cu0.w + cu1.w};
        BFLY(a, 0, 1) BFLY(a, 2, 3) BFLY(a, 0, 2) BFLY(a, 1, 3)

        bufA[bW1      ] = a[0]; bufA[bW1 +  64] = a[1];
        bufA[bW1 + 128] = a[2]; bufA[bW1 + 192] = a[3];
        __syncthreads();

        if (t < 128) {   // round 1: bits {2,3,4}
            float b[8];
            const float4 v0 = *(const float4*)&bufA[bR1];
            const float4 v1 = *(const float4*)&bufA[bR1 + 32];
            b[0] = v0.x; b[1] = v0.y; b[2] = v0.z; b[3] = v0.w;
            b[4] = v1.x; b[5] = v1.y; b[6] = v1.z; b[7] = v1.w;
            RADIX8(b)
#pragma unroll
            for (int q = 0; q < 8; ++q) bufB[bW2 + 64 * q] = b[q];
        }
        __syncthreads();

        if (t < 128) {   // round 2: bits {5,6,7}
            float c[8];
            const float4 v0 = *(const float4*)&bufB[bR2];
            const float4 v1 = *(const float4*)&bufB[bR2 + 32];
            c[0] = v0.x; c[1] = v0.y; c[2] = v0.z; c[3] = v0.w;
            c[4] = v1.x; c[5] = v1.y; c[6] = v1.z; c[7] = v1.w;
            RADIX8(c)
#pragma unroll
            for (int q = 0; q < 8; ++q) bufA[bW3 + 64 * q] = c[q];
        }
        __syncthreads();

        {   // round 3: bits {8,9}; reg k holds y[t + 256k] (unscaled)
            const float4 v0 = *(const float4*)&bufA[bR3];
            float d[4] = {v0.x, v0.y, v0.z, v0.w};
            BFLY(d, 0, 1) BFLY(d, 2, 3) BFLY(d, 0, 2) BFLY(d, 1, 3)
            float* orow = out + (size_t)(bid * RPB + r) * OUT_CH;
            orow[t]       = d[0];
            orow[t + 256] = d[1];
            orow[t + 512] = d[2];
            if (t < 232) orow[t + 768] = d[3];
        }
        __syncthreads();   // bufA reused by next row's W1

        if (r + 1 < RPB) { cu0 = nu0; cu1 = nu1; }
    }

    // per-block sumsq partial (fixed order -> deterministic)
#pragma unroll
    for (int s = 32; s > 0; s >>= 1) ss += __shfl_xor(ss, s);
    if ((t & 63) == 0) wsf[t >> 6] = ss;
    __syncthreads();
    if (t == 0) partials[bid] = (wsf[0] + wsf[1]) + (wsf[2] + wsf[3]);
}

// ---------------------------------------------------------------------------
// Kernel 2: every block reduces all 2048 partials in the SAME double-precision
// order (bitwise-identical f everywhere, deterministic), then rescales its
// slice of out in place with float4.
// ---------------------------------------------------------------------------
__global__ __launch_bounds__(256) void rescale_kernel(const float* __restrict__ partials,
                                                      const float* __restrict__ scale,
                                                      float4* __restrict__ out4) {
    const int t = threadIdx.x;
    __shared__ double wsd[4];

    const float4* p4 = (const float4*)partials;
    const float4 q0 = p4[2 * t], q1 = p4[2 * t + 1];
    double acc = (double)q0.x + q0.y;
    acc += q0.z; acc += q0.w; acc += q1.x; acc += q1.y; acc += q1.z; acc += q1.w;
#pragma unroll
    for (int s = 32; s > 0; s >>= 1) acc += __shfl_xor(acc, s);
    if ((t & 63) == 0) wsd[t >> 6] = acc;
    __syncthreads();
    const double total = (wsd[0] + wsd[1]) + (wsd[2] + wsd[3]);
    const float f = (float)(-((double)(*scale)) / (sqrt(total) + 1e-8));

    const int n4 = (NROWS * OUT_CH) / 4;   // 2,048,000 float4s, base 16B-aligned
    const int stride = GRID1 * 256;        // 524,288
    int i = blockIdx.x * 256 + t;
#pragma unroll
    for (int k = 0; k < 4; ++k) {
        const int idx = i + k * stride;
        if (idx < n4) {
            float4 v = out4[idx];
            v.x *= f; v.y *= f; v.z *= f; v.w *= f;
            out4[idx] = v;
        }
    }
}

extern "C" void kernel_launch(void* const* d_in, const int* in_sizes, int n_in,
                              void* d_out, int out_size, void* d_ws, size_t ws_size,
                              hipStream_t stream) {
    const float* x     = (const float*)d_in[0];
    // d_in[1] = proj — unused: it is the Sylvester Hadamard matrix by
    // construction, so the einsum is a Fast Walsh-Hadamard Transform.
    const float* scale = (const float*)d_in[2];
    float* out      = (float*)d_out;
    float* partials = (float*)d_ws;   // 2048 floats

    fwht_sumsq_kernel<<<GRID1, 256, 0, stream>>>(x, out, partials);
    rescale_kernel<<<GRID1, 256, 0, stream>>>(partials, scale, (float4*)out);
}